// Round 7
// baseline (197.419 us; speedup 1.0000x reference)
//
#include <hip/hip_runtime.h>

#define CROP_H 14
#define CROP_W 14
#define IMG_B 8
#define IMG_C 256
#define IMG_H 100
#define IMG_W 152
#define NBOX 1000
#define PLANE (IMG_H * IMG_W)                 // 15200
#define POS (CROP_H * CROP_W)                 // 196
#define OUT_PER_BOX (IMG_C * POS)             // 50176
#define CG 32                                 // fallback: channels per block
#define NCG (IMG_C / CG)
#define G64 4                                 // 64-channel groups
#define IMGT_BYTES ((size_t)IMG_B * G64 * PLANE * 64 * 4)   // 124,518,400
#define WS_NEED (IMGT_BYTES + NBOX * sizeof(int))

typedef float f2u __attribute__((ext_vector_type(2), aligned(4)));

// ---------------------------------------------------------------------------
// Kernel A: stable counting-sort of boxes by box_ind -> perm (deterministic).
// ---------------------------------------------------------------------------
__global__ __launch_bounds__(1024) void sort_boxes_kernel(
    const int* __restrict__ box_ind,
    int* __restrict__ perm)
{
    __shared__ unsigned s_mask[IMG_B][32];
    __shared__ int s_tot[IMG_B];
    const int tid = threadIdx.x;

    if (tid < IMG_B * 32) ((unsigned*)s_mask)[tid] = 0u;
    __syncthreads();

    int key = 0;
    if (tid < NBOX) {
        key = box_ind[tid];
        atomicOr(&s_mask[key][tid >> 5], 1u << (tid & 31));
    }
    __syncthreads();

    if (tid < IMG_B) {
        int t = 0;
        #pragma unroll
        for (int w = 0; w < 32; ++w) t += __popc(s_mask[tid][w]);
        s_tot[tid] = t;
    }
    __syncthreads();

    if (tid < NBOX) {
        int base = 0;
        #pragma unroll
        for (int k = 0; k < IMG_B; ++k) base += (k < key) ? s_tot[k] : 0;
        const int w = tid >> 5, b = tid & 31;
        int r = __popc(s_mask[key][w] & ((b == 0) ? 0u : ((1u << b) - 1u)));
        for (int ww = 0; ww < w; ++ww) r += __popc(s_mask[key][ww]);
        perm[base + r] = tid;
    }
}

// ---------------------------------------------------------------------------
// Kernel T: CHW -> [b][g][pos][64c] transpose. LDS 64x65 tile; both global
// phases fully coalesced (256 B per wave-instr).
// ---------------------------------------------------------------------------
__global__ __launch_bounds__(256) void transpose_kernel(
    const float* __restrict__ img, float* __restrict__ imgT)
{
    __shared__ float tile[64][65];
    const int pos0 = blockIdx.x * 64;
    const int g = blockIdx.y, b = blockIdx.z;
    const int lane = threadIdx.x & 63, warp = threadIdx.x >> 6;

    const int pos_r = pos0 + lane;
    #pragma unroll
    for (int i = 0; i < 16; ++i) {
        const int cl = warp * 16 + i;
        float v = 0.0f;
        if (pos_r < PLANE)
            v = img[((size_t)(b * IMG_C + g * 64 + cl)) * PLANE + pos_r];
        tile[lane][cl] = v;
    }
    __syncthreads();
    #pragma unroll
    for (int i = 0; i < 16; ++i) {
        const int pl = warp * 16 + i;
        const int pos = pos0 + pl;
        if (pos < PLANE)
            imgT[(((size_t)(b * G64 + g)) * PLANE + pos) * 64 + lane] = tile[pl][lane];
    }
}

// ---------------------------------------------------------------------------
// Kernel B (HWC main): block = (box, 64ch group). lane = channel -> all corner
// loads fully coalesced (256 B). Results staged in LDS, written out c-major
// coalesced. bid&7 keeps (group, image-half) per XCD; sorted slots keep the
// per-XCD read working set ~3.9 MB (fits 4 MB L2).
// ---------------------------------------------------------------------------
__global__ __launch_bounds__(256) void crop_hwc_kernel(
    const float* __restrict__ imgT,
    const float* __restrict__ boxes,
    const int* __restrict__ box_ind,
    const int* __restrict__ perm,
    float* __restrict__ out)
{
    __shared__ int   s_pack[POS];
    __shared__ float s_xw[POS], s_yw[POS];
    __shared__ float stile[28][65];

    const int bid  = blockIdx.x;
    const int k    = bid & 7;                 // XCD under round-robin dispatch
    const int g    = k & 3;                   // channel group
    const int slot = (k >> 2) * 500 + (bid >> 3);
    const int tid  = threadIdx.x;
    const int lane = tid & 63, warp = tid >> 6;

    const int n = perm[slot];                 // uniform -> scalar
    const int b = box_ind[n];

    if (tid < POS) {
        const int y = tid / CROP_W;
        const int x = tid - y * CROP_W;

        const float y1 = boxes[n * 4 + 0];
        const float x1 = boxes[n * 4 + 1];
        const float y2 = boxes[n * 4 + 2];
        const float x2 = boxes[n * 4 + 3];

        // exact fp32 RN, no FMA — must match numpy bitwise (validity is
        // discontinuous)
        const float hs   = __fdiv_rn(__fmul_rn(__fsub_rn(y2, y1), (float)(IMG_H - 1)),
                                     (float)(CROP_H - 1));
        const float in_y = __fadd_rn(__fmul_rn(y1, (float)(IMG_H - 1)),
                                     __fmul_rn((float)y, hs));
        const int vy = (in_y >= 0.0f) && (in_y <= (float)(IMG_H - 1));
        const float top = floorf(in_y);
        const float ylp = __fsub_rn(in_y, top);
        const int ti = (int)fminf(fmaxf(top, 0.0f), (float)(IMG_H - 1));

        const float ws   = __fdiv_rn(__fmul_rn(__fsub_rn(x2, x1), (float)(IMG_W - 1)),
                                     (float)(CROP_W - 1));
        const float in_x = __fadd_rn(__fmul_rn(x1, (float)(IMG_W - 1)),
                                     __fmul_rn((float)x, ws));
        const int vx = (in_x >= 0.0f) && (in_x <= (float)(IMG_W - 1));
        const float left = floorf(in_x);
        const float xlp = __fsub_rn(in_x, left);
        const int li = (int)fminf(fmaxf(left, 0.0f), (float)(IMG_W - 1));

        const int r0   = min(ti, IMG_H - 2);
        const int c0   = min(li, IMG_W - 2);
        const int sely = (ti == IMG_H - 1);
        const int selx = (li == IMG_W - 1);
        const int off  = r0 * IMG_W + c0;       // fits 14 bits

        s_pack[tid] = off | (selx << 14) | (sely << 15) | (((vy & vx)) << 16);
        s_xw[tid] = xlp;
        s_yw[tid] = ylp;
    }
    __syncthreads();

    const float* __restrict__ base_img =
        imgT + ((size_t)(b * G64 + g)) * ((size_t)PLANE * 64);
    float* __restrict__ out_g =
        out + (size_t)n * OUT_PER_BOX + (size_t)(g * 64) * POS;

    for (int ch = 0; ch < 7; ++ch) {          // 7 chunks x 28 positions = 196
        const int p0 = ch * 28;

        #pragma unroll
        for (int q = 0; q < 7; ++q) {
            const int pl = warp * 7 + q;       // 0..27
            const int p  = p0 + pl;
            const int w  = s_pack[p];          // wave-uniform broadcast
            const float xw = s_xw[p], yw = s_yw[p];

            const float* pp  = base_img + (size_t)(w & 0x3FFF) * 64 + lane;
            const float* pp2 = pp + IMG_W * 64;
            const float tl0 = pp[0];
            const float tr0 = pp[64];
            const float bl  = pp2[0];
            const float br  = pp2[64];

            // clamp selects: sely -> both rows are the bottom row;
            //                selx -> both cols are the right col
            const float tA = (w & 0x8000) ? bl : tl0;
            const float tB = (w & 0x8000) ? br : tr0;
            const float tl = (w & 0x4000) ? tB : tA;
            const float blv = (w & 0x4000) ? br : bl;

            const float top_v = __fadd_rn(tl, __fmul_rn(__fsub_rn(tB, tl), xw));
            const float bot_v = __fadd_rn(blv, __fmul_rn(__fsub_rn(br, blv), xw));
            const float v = __fadd_rn(top_v, __fmul_rn(__fsub_rn(bot_v, top_v), yw));

            stile[pl][lane] = (w & 0x10000) ? v : 0.0f;
        }
        __syncthreads();

        // store 28x64 = 1792 = 7*256 elements, c-major runs (coalesced)
        #pragma unroll
        for (int it = 0; it < 7; ++it) {
            const int e  = it * 256 + tid;
            const int cl = e / 28;             // magic mul
            const int j  = e - cl * 28;
            out_g[cl * POS + p0 + j] = stile[j][cl];
        }
        __syncthreads();
    }
}

// ---------------------------------------------------------------------------
// Fallback (R5): register-state gather from CHW. Known 104 us.
// ---------------------------------------------------------------------------
__global__ __launch_bounds__(256) void crop_chw_kernel(
    const float* __restrict__ image,
    const float* __restrict__ boxes,
    const int* __restrict__ box_ind,
    const int* __restrict__ perm,
    int use_perm,
    float* __restrict__ out)
{
    const int bid  = blockIdx.x;
    const int cg   = bid & 7;
    const int slot = bid >> 3;
    const int tid  = threadIdx.x;
    if (tid >= POS) return;

    const int n = use_perm ? perm[slot] : slot;
    const int b = box_ind[n];

    const int y = tid / CROP_W;
    const int x = tid - y * CROP_W;

    const float y1 = boxes[n * 4 + 0];
    const float x1 = boxes[n * 4 + 1];
    const float y2 = boxes[n * 4 + 2];
    const float x2 = boxes[n * 4 + 3];

    const float hs   = __fdiv_rn(__fmul_rn(__fsub_rn(y2, y1), (float)(IMG_H - 1)),
                                 (float)(CROP_H - 1));
    const float in_y = __fadd_rn(__fmul_rn(y1, (float)(IMG_H - 1)),
                                 __fmul_rn((float)y, hs));
    const int vy = (in_y >= 0.0f) && (in_y <= (float)(IMG_H - 1));
    const float top = floorf(in_y);
    const float yw  = __fsub_rn(in_y, top);
    const int ti = (int)fminf(fmaxf(top, 0.0f), (float)(IMG_H - 1));

    const float ws   = __fdiv_rn(__fmul_rn(__fsub_rn(x2, x1), (float)(IMG_W - 1)),
                                 (float)(CROP_W - 1));
    const float in_x = __fadd_rn(__fmul_rn(x1, (float)(IMG_W - 1)),
                                 __fmul_rn((float)x, ws));
    const int vx = (in_x >= 0.0f) && (in_x <= (float)(IMG_W - 1));
    const float left = floorf(in_x);
    const float xw   = __fsub_rn(in_x, left);
    const int li = (int)fminf(fmaxf(left, 0.0f), (float)(IMG_W - 1));

    const int r0   = min(ti, IMG_H - 2);
    const int c0   = min(li, IMG_W - 2);
    const bool sely = (ti == IMG_H - 1);
    const bool selx = (li == IMG_W - 1);
    const bool vald = (vy & vx) != 0;

    const float* __restrict__ pl =
        image + (size_t)b * (size_t)(IMG_C * PLANE)
              + (size_t)(cg * CG) * PLANE + (r0 * IMG_W + c0);
    float* __restrict__ po =
        out + (size_t)n * (size_t)OUT_PER_BOX + (size_t)(cg * CG) * POS + tid;

    #pragma unroll 8
    for (int cl = 0; cl < CG; ++cl) {
        const f2u ra = *(const f2u*)(pl);
        const f2u rb = *(const f2u*)(pl + IMG_W);

        const float tA = sely ? rb.x : ra.x;
        const float tB = sely ? rb.y : ra.y;
        const float tl = selx ? tB : tA;
        const float bl = selx ? rb.y : rb.x;

        const float top_v = __fadd_rn(tl, __fmul_rn(__fsub_rn(tB, tl), xw));
        const float bot_v = __fadd_rn(bl, __fmul_rn(__fsub_rn(rb.y, bl), xw));
        const float v = __fadd_rn(top_v, __fmul_rn(__fsub_rn(bot_v, top_v), yw));

        *po = vald ? v : 0.0f;
        pl += PLANE;
        po += POS;
    }
}

extern "C" void kernel_launch(void* const* d_in, const int* in_sizes, int n_in,
                              void* d_out, int out_size, void* d_ws, size_t ws_size,
                              hipStream_t stream) {
    const float* image  = (const float*)d_in[0];
    const float* boxes  = (const float*)d_in[1];
    const int*   boxind = (const int*)d_in[2];
    float* out = (float*)d_out;

    if (ws_size >= WS_NEED) {
        float* imgT = (float*)d_ws;
        int*   perm = (int*)((char*)d_ws + IMGT_BYTES);

        sort_boxes_kernel<<<1, 1024, 0, stream>>>(boxind, perm);
        transpose_kernel<<<dim3((PLANE + 63) / 64, G64, IMG_B), 256, 0, stream>>>(
            image, imgT);
        crop_hwc_kernel<<<dim3(NBOX * G64), 256, 0, stream>>>(
            imgT, boxes, boxind, perm, out);
    } else {
        const int use_perm = (ws_size >= (size_t)(NBOX * sizeof(int))) ? 1 : 0;
        int* perm = (int*)d_ws;
        if (use_perm) sort_boxes_kernel<<<1, 1024, 0, stream>>>(boxind, perm);
        crop_chw_kernel<<<dim3(NBOX * NCG), 256, 0, stream>>>(
            image, boxes, boxind, perm, use_perm, out);
    }
}

// Round 8
// 101.380 us; speedup vs baseline: 1.9473x; 1.9473x over previous
//
#include <hip/hip_runtime.h>

#define CROP_H 14
#define CROP_W 14
#define IMG_B 8
#define IMG_C 256
#define IMG_H 100
#define IMG_W 152
#define NBOX 1000
#define PLANE (IMG_H * IMG_W)                 // 15200
#define POS (CROP_H * CROP_W)                 // 196
#define OUT_PER_BOX (IMG_C * POS)             // 50176
#define BOXCAP 256                            // boxes per param chunk
#define CG 32                                 // fallback path
#define NCG (IMG_C / CG)

typedef float f2u __attribute__((ext_vector_type(2), aligned(4)));

// ---------------------------------------------------------------------------
// Kernel A: stable counting-sort of boxes by box_ind -> perm + per-image
// offsets. Deterministic (atomicOr order-independent, popcount ranks).
// ---------------------------------------------------------------------------
__global__ __launch_bounds__(1024) void sort_boxes_kernel(
    const int* __restrict__ box_ind,
    int* __restrict__ perm,
    int* __restrict__ offsets)            // [IMG_B + 1]
{
    __shared__ unsigned s_mask[IMG_B][32];
    __shared__ int s_tot[IMG_B];
    const int tid = threadIdx.x;

    if (tid < IMG_B * 32) ((unsigned*)s_mask)[tid] = 0u;
    __syncthreads();

    int key = 0;
    if (tid < NBOX) {
        key = box_ind[tid];
        atomicOr(&s_mask[key][tid >> 5], 1u << (tid & 31));
    }
    __syncthreads();

    if (tid < IMG_B) {
        int t = 0;
        #pragma unroll
        for (int w = 0; w < 32; ++w) t += __popc(s_mask[tid][w]);
        s_tot[tid] = t;
    }
    __syncthreads();

    if (tid == 0) {
        int acc = 0;
        #pragma unroll
        for (int k = 0; k < IMG_B; ++k) { offsets[k] = acc; acc += s_tot[k]; }
        offsets[IMG_B] = acc;
    }

    if (tid < NBOX) {
        int base = 0;
        #pragma unroll
        for (int k = 0; k < IMG_B; ++k) base += (k < key) ? s_tot[k] : 0;
        const int w = tid >> 5, b = tid & 31;
        int r = __popc(s_mask[key][w] & ((b == 0) ? 0u : ((1u << b) - 1u)));
        for (int ww = 0; ww < w; ++ww) r += __popc(s_mask[key][ww]);
        perm[base + r] = tid;
    }
}

// ---------------------------------------------------------------------------
// Kernel B: plane-in-LDS crop-and-resize.
// Block = (channel, image). Stage the whole 100x152 fp32 plane (60.8 KB) into
// LDS once (each plane read from HBM exactly once, fully coalesced), then
// every box of the image gathers from LDS. Per-box derived params staged in
// LDS by a setup phase. Output: consecutive lanes -> consecutive positions
// within a (box, channel) run -> coalesced stores.
// ---------------------------------------------------------------------------
__global__ __launch_bounds__(512, 4) void CropAndResize_16630113370849_kernel(
    const float* __restrict__ image,
    const float* __restrict__ boxes,
    const int* __restrict__ perm,
    const int* __restrict__ offsets,
    float* __restrict__ out)
{
    __shared__ __align__(16) float s_plane[PLANE];
    __shared__ float s_hs[BOXCAP], s_ws[BOXCAP], s_y1H[BOXCAP], s_x1W[BOXCAP];
    __shared__ int   s_n[BOXCAP];

    const int c   = blockIdx.x;              // channel 0..255
    const int b   = blockIdx.y;              // image 0..7
    const int tid = threadIdx.x;

    // stage plane: 15200 floats = 3800 float4, coalesced
    {
        const float4* __restrict__ src =
            (const float4*)(image + ((size_t)b * IMG_C + c) * PLANE);
        float4* dst = (float4*)s_plane;
        #pragma unroll
        for (int i = 0; i < 8; ++i) {
            const int e = i * 512 + tid;
            if (e < PLANE / 4) dst[e] = src[e];
        }
    }

    const int s0 = offsets[b], s1 = offsets[b + 1];

    for (int ck = s0; ck < s1; ck += BOXCAP) {
        const int cnt = min(BOXCAP, s1 - ck);

        __syncthreads();   // plane ready (1st iter) / prev chunk compute done
        if (tid < cnt) {
            const int n = perm[ck + tid];
            const float y1 = boxes[n * 4 + 0];
            const float x1 = boxes[n * 4 + 1];
            const float y2 = boxes[n * 4 + 2];
            const float x2 = boxes[n * 4 + 3];
            // exact fp32 RN, no FMA — must match numpy bitwise (validity is
            // discontinuous in in_y/in_x)
            s_hs[tid]  = __fdiv_rn(__fmul_rn(__fsub_rn(y2, y1), (float)(IMG_H - 1)),
                                   (float)(CROP_H - 1));
            s_ws[tid]  = __fdiv_rn(__fmul_rn(__fsub_rn(x2, x1), (float)(IMG_W - 1)),
                                   (float)(CROP_W - 1));
            s_y1H[tid] = __fmul_rn(y1, (float)(IMG_H - 1));
            s_x1W[tid] = __fmul_rn(x1, (float)(IMG_W - 1));
            s_n[tid]   = n;
        }
        __syncthreads();

        const int total = cnt * POS;
        #pragma unroll 2
        for (int idx = tid; idx < total; idx += 512) {
            const int slot = idx / POS;          // magic mul
            const int p    = idx - slot * POS;
            const int y    = p / CROP_W;         // magic mul
            const int x    = p - y * CROP_W;

            const float in_y = __fadd_rn(s_y1H[slot],
                                         __fmul_rn((float)y, s_hs[slot]));
            const int vy = (in_y >= 0.0f) && (in_y <= (float)(IMG_H - 1));
            const float top = floorf(in_y);
            const float yw  = __fsub_rn(in_y, top);
            const int ti = (int)fminf(fmaxf(top, 0.0f), (float)(IMG_H - 1));

            const float in_x = __fadd_rn(s_x1W[slot],
                                         __fmul_rn((float)x, s_ws[slot]));
            const int vx = (in_x >= 0.0f) && (in_x <= (float)(IMG_W - 1));
            const float left = floorf(in_x);
            const float xw   = __fsub_rn(in_x, left);
            const int li = (int)fminf(fmaxf(left, 0.0f), (float)(IMG_W - 1));

            // 2x2 base: rows r0, r0+1; cols c0, c0+1; clamps become selects
            const int r0 = min(ti, IMG_H - 2);
            const int c0 = min(li, IMG_W - 2);
            const bool sely = (ti == IMG_H - 1);
            const bool selx = (li == IMG_W - 1);
            const bool vald = (vy & vx) != 0;

            const int off = r0 * IMG_W + c0;
            const float a0 = s_plane[off];
            const float a1 = s_plane[off + 1];
            const float b0 = s_plane[off + IMG_W];
            const float b1 = s_plane[off + IMG_W + 1];

            const float tA = sely ? b0 : a0;
            const float tB = sely ? b1 : a1;
            const float tl = selx ? tB : tA;
            const float bl = selx ? b1 : b0;

            const float top_v = __fadd_rn(tl, __fmul_rn(__fsub_rn(tB, tl), xw));
            const float bot_v = __fadd_rn(bl, __fmul_rn(__fsub_rn(b1, bl), xw));
            const float v = __fadd_rn(top_v, __fmul_rn(__fsub_rn(bot_v, top_v), yw));

            out[(size_t)s_n[slot] * OUT_PER_BOX + c * POS + p] = vald ? v : 0.0f;
        }
    }
}

// ---------------------------------------------------------------------------
// Fallback (R5 structure, known 104 us) if workspace is too small.
// ---------------------------------------------------------------------------
__global__ __launch_bounds__(256) void crop_chw_kernel(
    const float* __restrict__ image,
    const float* __restrict__ boxes,
    const int* __restrict__ box_ind,
    float* __restrict__ out)
{
    const int bid  = blockIdx.x;
    const int cg   = bid & 7;
    const int n    = bid >> 3;
    const int tid  = threadIdx.x;
    if (tid >= POS) return;

    const int b = box_ind[n];
    const int y = tid / CROP_W;
    const int x = tid - y * CROP_W;

    const float y1 = boxes[n * 4 + 0];
    const float x1 = boxes[n * 4 + 1];
    const float y2 = boxes[n * 4 + 2];
    const float x2 = boxes[n * 4 + 3];

    const float hs   = __fdiv_rn(__fmul_rn(__fsub_rn(y2, y1), (float)(IMG_H - 1)),
                                 (float)(CROP_H - 1));
    const float in_y = __fadd_rn(__fmul_rn(y1, (float)(IMG_H - 1)),
                                 __fmul_rn((float)y, hs));
    const int vy = (in_y >= 0.0f) && (in_y <= (float)(IMG_H - 1));
    const float top = floorf(in_y);
    const float yw  = __fsub_rn(in_y, top);
    const int ti = (int)fminf(fmaxf(top, 0.0f), (float)(IMG_H - 1));

    const float ws   = __fdiv_rn(__fmul_rn(__fsub_rn(x2, x1), (float)(IMG_W - 1)),
                                 (float)(CROP_W - 1));
    const float in_x = __fadd_rn(__fmul_rn(x1, (float)(IMG_W - 1)),
                                 __fmul_rn((float)x, ws));
    const int vx = (in_x >= 0.0f) && (in_x <= (float)(IMG_W - 1));
    const float left = floorf(in_x);
    const float xw   = __fsub_rn(in_x, left);
    const int li = (int)fminf(fmaxf(left, 0.0f), (float)(IMG_W - 1));

    const int r0 = min(ti, IMG_H - 2);
    const int c0 = min(li, IMG_W - 2);
    const bool sely = (ti == IMG_H - 1);
    const bool selx = (li == IMG_W - 1);
    const bool vald = (vy & vx) != 0;

    const float* __restrict__ pl =
        image + (size_t)b * (size_t)(IMG_C * PLANE)
              + (size_t)(cg * CG) * PLANE + (r0 * IMG_W + c0);
    float* __restrict__ po =
        out + (size_t)n * (size_t)OUT_PER_BOX + (size_t)(cg * CG) * POS + tid;

    #pragma unroll 8
    for (int cl = 0; cl < CG; ++cl) {
        const f2u ra = *(const f2u*)(pl);
        const f2u rb = *(const f2u*)(pl + IMG_W);
        const float tA = sely ? rb.x : ra.x;
        const float tB = sely ? rb.y : ra.y;
        const float tl = selx ? tB : tA;
        const float bl = selx ? rb.y : rb.x;
        const float top_v = __fadd_rn(tl, __fmul_rn(__fsub_rn(tB, tl), xw));
        const float bot_v = __fadd_rn(bl, __fmul_rn(__fsub_rn(rb.y, bl), xw));
        const float v = __fadd_rn(top_v, __fmul_rn(__fsub_rn(bot_v, top_v), yw));
        *po = vald ? v : 0.0f;
        pl += PLANE;
        po += POS;
    }
}

extern "C" void kernel_launch(void* const* d_in, const int* in_sizes, int n_in,
                              void* d_out, int out_size, void* d_ws, size_t ws_size,
                              hipStream_t stream) {
    const float* image  = (const float*)d_in[0];
    const float* boxes  = (const float*)d_in[1];
    const int*   boxind = (const int*)d_in[2];
    float* out = (float*)d_out;

    const size_t need = (NBOX + IMG_B + 1) * sizeof(int);
    if (ws_size >= need) {
        int* perm    = (int*)d_ws;
        int* offsets = perm + NBOX;

        sort_boxes_kernel<<<1, 1024, 0, stream>>>(boxind, perm, offsets);
        CropAndResize_16630113370849_kernel<<<dim3(IMG_C, IMG_B), 512, 0, stream>>>(
            image, boxes, perm, offsets, out);
    } else {
        crop_chw_kernel<<<dim3(NBOX * NCG), 256, 0, stream>>>(
            image, boxes, boxind, out);
    }
}